// Round 7
// baseline (4027.887 us; speedup 1.0000x reference)
//
#include <hip/hip_runtime.h>
#include <math.h>

#define CH 8
#define NH 4
#define HID 4
#define SPATIAL 65536        // 256*256 floats per slice
#define NSLICE 1024          // 32*4*8 slices
#define NBATCH 32
#define BPS 8                // blocks per slice
#define NBLK (NSLICE*BPS)    // 8192 blocks
#define CHUNK4 2048          // float4 per block (8192 floats)
#define BPB 256              // blocks per batch (32 slices * 8)
#define EPS 1e-5f

typedef float nf4 __attribute__((ext_vector_type(4)));

// Single-pass persistent-style kernel: each block loads its 8192-float chunk
// into REGISTERS (8 float4/thread), contributes a partial sum, and the
// last-arriving block of each batch (device-scope counter) computes the
// batch's 4x8 attention factor and release-publishes it; siblings
// acquire-spin with s_sleep backoff, then scale their in-register data and
// nt-store. x is fetched from HBM exactly once.
// NOTE: forward progress relies on workgroups dispatching in ascending
// blockIdx order (resident prefix completes -> frees slots) — standard for
// producer/consumer kernels; batches are 256 consecutive blocks.
__global__ __launch_bounds__(256, 4)
void fused_onepass(const float* __restrict__ x,
                   const float* __restrict__ Wq, const float* __restrict__ Wk,
                   const float* __restrict__ Wv, const float* __restrict__ Wo,
                   const float* __restrict__ bo,
                   const float* __restrict__ W1, const float* __restrict__ b1,
                   const float* __restrict__ W2, const float* __restrict__ b2,
                   const float* __restrict__ g1, const float* __restrict__ beta1,
                   const float* __restrict__ g2, const float* __restrict__ beta2,
                   const float* __restrict__ gate,
                   float* __restrict__ out,
                   float* __restrict__ psum,    // [NBLK] per-block partials
                   float* __restrict__ facg,    // [NBATCH*32] factors
                   int*   __restrict__ count,   // [NBATCH*32] arrival ctr (stride 32)
                   int*   __restrict__ flag) {  // [NBATCH*32] ready flag  (stride 32)
    const int blk   = blockIdx.x;
    const int slice = blk >> 3;          // ((b*4+h)*8+c)
    const int q     = blk & 7;
    const int b     = slice >> 5;
    const int hh    = (slice >> 3) & 3;
    const int cc    = slice & 7;
    const int tid   = threadIdx.x;

    const size_t base = (size_t)slice * (SPATIAL / 4) + (size_t)q * CHUNK4;
    const nf4* xs = (const nf4*)x + base;

    // ---- load chunk into registers (stays live to the end) ----
    nf4 r0 = xs[tid],        r1 = xs[tid + 256],  r2 = xs[tid + 512],  r3 = xs[tid + 768];
    nf4 r4 = xs[tid + 1024], r5 = xs[tid + 1280], r6 = xs[tid + 1536], r7 = xs[tid + 1792];

    // ---- block partial sum ----
    nf4 a = ((r0 + r1) + (r2 + r3)) + ((r4 + r5) + (r6 + r7));
    float sum = (a.x + a.y) + (a.z + a.w);
    for (int off = 32; off; off >>= 1) sum += __shfl_down(sum, off, 64);
    __shared__ float part[4];
    __shared__ float fac_me;
    __shared__ int   is_last;
    if ((tid & 63) == 0) part[tid >> 6] = sum;
    __syncthreads();
    if (tid == 0) {
        psum[blk] = (part[0] + part[1]) + (part[2] + part[3]);
        __threadfence();                 // psum visible before counter bump
        int old = __hip_atomic_fetch_add(&count[b * 32], 1,
                                         __ATOMIC_ACQ_REL, __HIP_MEMORY_SCOPE_AGENT);
        is_last = (old == BPB - 1);
    }
    __syncthreads();

    if (is_last) {
        if (tid == 0) {
            // ---- whole-batch tiny attention, single thread ----
            const float* ps = psum + (size_t)b * BPB;   // 32 slices * 8 parts
            float xp[NH][CH];
#pragma unroll
            for (int h = 0; h < NH; ++h)
#pragma unroll
                for (int c = 0; c < CH; ++c) {
                    const float* pp = ps + (h * CH + c) * BPS;
                    float s = ((pp[0] + pp[1]) + (pp[2] + pp[3]))
                            + ((pp[4] + pp[5]) + (pp[6] + pp[7]));
                    xp[h][c] = s * (1.0f / SPATIAL);
                }
            float Qm[NH][CH], Km[NH][CH], Vm[NH][CH];
#pragma unroll
            for (int h = 0; h < NH; ++h) {
                float mu = 0.f;
#pragma unroll
                for (int c = 0; c < CH; ++c) mu += xp[h][c];
                mu *= 0.125f;
                float var = 0.f;
#pragma unroll
                for (int c = 0; c < CH; ++c) { float d = xp[h][c] - mu; var += d * d; }
                var *= 0.125f;
                float rs = rsqrtf(var + EPS);
                float xn[CH];
#pragma unroll
                for (int c = 0; c < CH; ++c) xn[c] = (xp[h][c] - mu) * rs * g1[c] + beta1[c];
#pragma unroll
                for (int c = 0; c < CH; ++c) {
                    float qq = 0.f, kk = 0.f, vv = 0.f;
#pragma unroll
                    for (int j = 0; j < CH; ++j) {
                        qq += xn[j] * Wq[c * CH + j];
                        kk += xn[j] * Wk[c * CH + j];
                        vv += xn[j] * Wv[c * CH + j];
                    }
                    Qm[h][c] = qq; Km[h][c] = kk; Vm[h][c] = vv;
                }
            }
            const float gs = 1.0f / (1.0f + __expf(-gate[0]));
            float fo[NH][CH];
#pragma unroll
            for (int h = 0; h < NH; ++h) {
                float sc[NH], mx = -1e30f;
#pragma unroll
                for (int g = 0; g < NH; ++g) {
                    float s = 0.f;
#pragma unroll
                    for (int c = 0; c < CH; ++c) s += Qm[h][c] * Km[g][c];
                    s *= 0.35355339059327373f;    // CH^-0.5
                    sc[g] = s; mx = fmaxf(mx, s);
                }
                float den = 0.f;
#pragma unroll
                for (int g = 0; g < NH; ++g) { sc[g] = __expf(sc[g] - mx); den += sc[g]; }
                const float inv = 1.0f / den;
                float ao[CH];
#pragma unroll
                for (int c = 0; c < CH; ++c) {
                    float aa = 0.f;
#pragma unroll
                    for (int g = 0; g < NH; ++g) aa += sc[g] * Vm[g][c];
                    ao[c] = aa * inv;
                }
                float xa[CH];
#pragma unroll
                for (int c = 0; c < CH; ++c) {
                    float o = bo[c];
#pragma unroll
                    for (int j = 0; j < CH; ++j) o += ao[j] * Wo[c * CH + j];
                    xa[c] = xp[h][c] + o;
                }
                float mu = 0.f;
#pragma unroll
                for (int c = 0; c < CH; ++c) mu += xa[c];
                mu *= 0.125f;
                float var = 0.f;
#pragma unroll
                for (int c = 0; c < CH; ++c) { float d = xa[c] - mu; var += d * d; }
                var *= 0.125f;
                float rs = rsqrtf(var + EPS);
                float xn2[CH];
#pragma unroll
                for (int c = 0; c < CH; ++c) xn2[c] = (xa[c] - mu) * rs * g2[c] + beta2[c];
                float h1v[HID];
#pragma unroll
                for (int i = 0; i < HID; ++i) {
                    float t = b1[i];
#pragma unroll
                    for (int c = 0; c < CH; ++c) t += xn2[c] * W1[i * CH + c];
                    h1v[i] = 0.5f * t * (1.0f + erff(t * 0.70710678118654752f));
                }
#pragma unroll
                for (int c = 0; c < CH; ++c) {
                    float ff = b2[c];
#pragma unroll
                    for (int i = 0; i < HID; ++i) ff += h1v[i] * W2[c * HID + i];
                    float xo = xa[c] + ff;
                    fo[h][c] = 1.0f + gs * (xo - xp[h][c]) + xp[h][c];
                }
            }
#pragma unroll
            for (int h = 0; h < NH; ++h)
#pragma unroll
                for (int c = 0; c < CH; ++c) facg[b * 32 + h * CH + c] = fo[h][c];
            __threadfence();              // factors visible before flag
            __hip_atomic_store(&flag[b * 32], 1,
                               __ATOMIC_RELEASE, __HIP_MEMORY_SCOPE_AGENT);
            fac_me = fo[hh][cc];
        }
    } else {
        if (tid == 0) {
            while (__hip_atomic_load(&flag[b * 32],
                                     __ATOMIC_ACQUIRE, __HIP_MEMORY_SCOPE_AGENT) == 0)
                __builtin_amdgcn_s_sleep(32);
            fac_me = facg[b * 32 + hh * CH + cc];
        }
    }
    __syncthreads();

    // ---- scale in-register data and stream out ----
    const float f = fac_me;
    nf4* os = (nf4*)out + base;
    r0 *= f; r1 *= f; r2 *= f; r3 *= f; r4 *= f; r5 *= f; r6 *= f; r7 *= f;
    __builtin_nontemporal_store(r0, &os[tid]);
    __builtin_nontemporal_store(r1, &os[tid + 256]);
    __builtin_nontemporal_store(r2, &os[tid + 512]);
    __builtin_nontemporal_store(r3, &os[tid + 768]);
    __builtin_nontemporal_store(r4, &os[tid + 1024]);
    __builtin_nontemporal_store(r5, &os[tid + 1280]);
    __builtin_nontemporal_store(r6, &os[tid + 1536]);
    __builtin_nontemporal_store(r7, &os[tid + 1792]);
}

extern "C" void kernel_launch(void* const* d_in, const int* in_sizes, int n_in,
                              void* d_out, int out_size, void* d_ws, size_t ws_size,
                              hipStream_t stream) {
    const float* x     = (const float*)d_in[0];
    const float* Wq    = (const float*)d_in[1];
    const float* Wk    = (const float*)d_in[2];
    const float* Wv    = (const float*)d_in[3];
    const float* Wo    = (const float*)d_in[4];
    const float* bo    = (const float*)d_in[5];
    const float* W1    = (const float*)d_in[6];
    const float* b1    = (const float*)d_in[7];
    const float* W2    = (const float*)d_in[8];
    const float* b2    = (const float*)d_in[9];
    const float* g1    = (const float*)d_in[10];
    const float* beta1 = (const float*)d_in[11];
    const float* g2    = (const float*)d_in[12];
    const float* beta2 = (const float*)d_in[13];
    const float* gate  = (const float*)d_in[14];
    float* out = (float*)d_out;

    // ws layout: psum[8192] f | facg[1024] f | count[1024] i | flag[1024] i
    float* psum  = (float*)d_ws;
    float* facg  = psum + NBLK;
    int*   count = (int*)(facg + NBATCH * 32);
    int*   flag  = count + NBATCH * 32;

    // zero counters+flags every launch (graph-capture safe)
    hipMemsetAsync(count, 0, 2 * NBATCH * 32 * sizeof(int), stream);

    fused_onepass<<<NBLK, 256, 0, stream>>>(x, Wq, Wk, Wv, Wo, bo,
                                            W1, b1, W2, b2,
                                            g1, beta1, g2, beta2, gate,
                                            out, psum, facg, count, flag);
}

// Round 8
// 151.765 us; speedup vs baseline: 26.5402x; 26.5402x over previous
//
#include <hip/hip_runtime.h>
#include <math.h>

#define CH 8
#define NH 4
#define HID 4
#define SPATIAL 65536       // 256*256
#define NSLICE 1024         // 32*4*8
#define NHALF  2048         // 2 half-slices per slice
#define HALF4  8192         // float4 per half-slice (32768 floats)
#define QHALF  512          // half-slices per quarter of x
#define EPS 1e-5f

typedef float nf4 __attribute__((ext_vector_type(4)));

// ---------------- Kernel 1: spatial sum pool (half-slice granularity) ----------------
// 2048 blocks x 256 threads; streams x forward at full BW.
__global__ __launch_bounds__(256)
void pool_kernel(const float* __restrict__ x, float* __restrict__ partial) {
    const int half = blockIdx.x;
    const nf4* xs = (const nf4*)x + (size_t)half * HALF4;
    const int tid = threadIdx.x;

    nf4 a0 = {0,0,0,0}, a1 = {0,0,0,0}, a2 = {0,0,0,0}, a3 = {0,0,0,0};
    int k = tid;
#pragma unroll
    for (int it = 0; it < 8; ++it) {      // 32 float4 per thread
        a0 += xs[k];
        a1 += xs[k + 256];
        a2 += xs[k + 512];
        a3 += xs[k + 768];
        k += 1024;
    }
    nf4 a = (a0 + a1) + (a2 + a3);
    float sum = (a.x + a.y) + (a.z + a.w);

    for (int off = 32; off; off >>= 1) sum += __shfl_down(sum, off, 64);
    __shared__ float part[4];
    if ((tid & 63) == 0) part[tid >> 6] = sum;
    __syncthreads();
    if (tid == 0)
        partial[half] = (part[0] + part[1]) + (part[2] + part[3]);
}

// ---------------- Kernel 2: factor-compute + scale, one QUARTER of x ----------------
// 512 blocks x 256 threads; block = one half-slice (32768 floats, 32 float4/thread).
// Launched 4x in reverse quarter order so each launch's 67 MB read set is
// MRU-resident in the 256 MB Infinity Cache. nt-stores don't evict x.
__global__ __launch_bounds__(256)
void scale_fused(const float* __restrict__ x,
                 const float* __restrict__ partial,
                 const float* __restrict__ Wq, const float* __restrict__ Wk,
                 const float* __restrict__ Wv, const float* __restrict__ Wo,
                 const float* __restrict__ bo,
                 const float* __restrict__ W1, const float* __restrict__ b1,
                 const float* __restrict__ W2, const float* __restrict__ b2,
                 const float* __restrict__ g1, const float* __restrict__ beta1,
                 const float* __restrict__ g2, const float* __restrict__ beta2,
                 const float* __restrict__ gate,
                 float* __restrict__ out,
                 int half_base) {
    const int half  = half_base + blockIdx.x;
    const int slice = half >> 1;         // (b*4 + h)*8 + c
    const int b     = slice >> 5;
    const int hh    = (slice >> 3) & 3;
    const int cc    = slice & 7;
    const int tid   = threadIdx.x;

    __shared__ float Kl[NH][CH], Vl[NH][CH], fac[NH][CH];

    float xp[CH], Q[CH];
    if (tid < NH) {
        // pooled row h = tid of batch b, from half-partials
        const float* pr = partial + b * (NH * CH * 2) + tid * (CH * 2);
#pragma unroll
        for (int c = 0; c < CH; ++c)
            xp[c] = (pr[c * 2] + pr[c * 2 + 1]) * (1.0f / SPATIAL);
        // LayerNorm 1
        float mu = 0.f;
#pragma unroll
        for (int c = 0; c < CH; ++c) mu += xp[c];
        mu *= 0.125f;
        float var = 0.f;
#pragma unroll
        for (int c = 0; c < CH; ++c) { float d = xp[c] - mu; var += d * d; }
        var *= 0.125f;
        float rs = rsqrtf(var + EPS);
        float xn[CH];
#pragma unroll
        for (int c = 0; c < CH; ++c) xn[c] = (xp[c] - mu) * rs * g1[c] + beta1[c];
        // Q,K,V
#pragma unroll
        for (int c = 0; c < CH; ++c) {
            float q = 0.f, k = 0.f, v = 0.f;
#pragma unroll
            for (int j = 0; j < CH; ++j) {
                q += xn[j] * Wq[c * CH + j];
                k += xn[j] * Wk[c * CH + j];
                v += xn[j] * Wv[c * CH + j];
            }
            Q[c] = q; Kl[tid][c] = k; Vl[tid][c] = v;
        }
    }
    __syncthreads();
    if (tid < NH) {
        float sc[NH], mx = -1e30f;
#pragma unroll
        for (int g = 0; g < NH; ++g) {
            float s = 0.f;
#pragma unroll
            for (int c = 0; c < CH; ++c) s += Q[c] * Kl[g][c];
            s *= 0.35355339059327373f;   // CH^-0.5
            sc[g] = s; mx = fmaxf(mx, s);
        }
        float den = 0.f;
#pragma unroll
        for (int g = 0; g < NH; ++g) { sc[g] = __expf(sc[g] - mx); den += sc[g]; }
        const float inv = 1.0f / den;
        float ao[CH];
#pragma unroll
        for (int c = 0; c < CH; ++c) {
            float a = 0.f;
#pragma unroll
            for (int g = 0; g < NH; ++g) a += sc[g] * Vl[g][c];
            ao[c] = a * inv;
        }
        // out proj + residual
        float xa[CH];
#pragma unroll
        for (int c = 0; c < CH; ++c) {
            float o = bo[c];
#pragma unroll
            for (int j = 0; j < CH; ++j) o += ao[j] * Wo[c * CH + j];
            xa[c] = xp[c] + o;
        }
        // LayerNorm 2
        float mu = 0.f;
#pragma unroll
        for (int c = 0; c < CH; ++c) mu += xa[c];
        mu *= 0.125f;
        float var = 0.f;
#pragma unroll
        for (int c = 0; c < CH; ++c) { float d = xa[c] - mu; var += d * d; }
        var *= 0.125f;
        float rs = rsqrtf(var + EPS);
        float xn2[CH];
#pragma unroll
        for (int c = 0; c < CH; ++c) xn2[c] = (xa[c] - mu) * rs * g2[c] + beta2[c];
        // FFN (exact gelu)
        float h1[HID];
#pragma unroll
        for (int i = 0; i < HID; ++i) {
            float t = b1[i];
#pragma unroll
            for (int c = 0; c < CH; ++c) t += xn2[c] * W1[i * CH + c];
            h1[i] = 0.5f * t * (1.0f + erff(t * 0.70710678118654752f));
        }
        const float gs = 1.0f / (1.0f + __expf(-gate[0]));
#pragma unroll
        for (int c = 0; c < CH; ++c) {
            float f = b2[c];
#pragma unroll
            for (int i = 0; i < HID; ++i) f += h1[i] * W2[c * HID + i];
            float xo = xa[c] + f;
            fac[tid][c] = 1.0f + gs * (xo - xp[c]) + xp[c];
        }
    }
    __syncthreads();
    const float f = fac[hh][cc];

    const nf4* xs = (const nf4*)x + (size_t)half * HALF4;
    nf4*       os = (nf4*)out     + (size_t)half * HALF4;
    int k = tid;
#pragma unroll
    for (int it = 0; it < 8; ++it) {      // 8 iters x 4 independent load+store
        nf4 v0 = xs[k];
        nf4 v1 = xs[k + 256];
        nf4 v2 = xs[k + 512];
        nf4 v3 = xs[k + 768];
        v0 *= f; v1 *= f; v2 *= f; v3 *= f;
        __builtin_nontemporal_store(v0, &os[k]);
        __builtin_nontemporal_store(v1, &os[k + 256]);
        __builtin_nontemporal_store(v2, &os[k + 512]);
        __builtin_nontemporal_store(v3, &os[k + 768]);
        k += 1024;
    }
}

extern "C" void kernel_launch(void* const* d_in, const int* in_sizes, int n_in,
                              void* d_out, int out_size, void* d_ws, size_t ws_size,
                              hipStream_t stream) {
    const float* x     = (const float*)d_in[0];
    const float* Wq    = (const float*)d_in[1];
    const float* Wk    = (const float*)d_in[2];
    const float* Wv    = (const float*)d_in[3];
    const float* Wo    = (const float*)d_in[4];
    const float* bo    = (const float*)d_in[5];
    const float* W1    = (const float*)d_in[6];
    const float* b1    = (const float*)d_in[7];
    const float* W2    = (const float*)d_in[8];
    const float* b2    = (const float*)d_in[9];
    const float* g1    = (const float*)d_in[10];
    const float* beta1 = (const float*)d_in[11];
    const float* g2    = (const float*)d_in[12];
    const float* beta2 = (const float*)d_in[13];
    const float* gate  = (const float*)d_in[14];
    float* out = (float*)d_out;

    float* partial = (float*)d_ws;           // NHALF floats

    pool_kernel<<<NHALF, 256, 0, stream>>>(x, partial);

    // scale quarters in REVERSE order: freshest-in-L3 first
    for (int qtr = 3; qtr >= 0; --qtr) {
        scale_fused<<<QHALF, 256, 0, stream>>>(x, partial,
                                               Wq, Wk, Wv, Wo, bo,
                                               W1, b1, W2, b2,
                                               g1, beta1, g2, beta2,
                                               gate, out, qtr * QHALF);
    }
}